// Round 6
// baseline (230.190 us; speedup 1.0000x reference)
//
#include <hip/hip_runtime.h>

// ---------------- types / helpers ----------------
typedef __attribute__((ext_vector_type(8))) short short8;   // 8 bf16 = 4 VGPRs (MFMA A/B frag)
typedef __attribute__((ext_vector_type(4))) short short4v;
typedef __attribute__((ext_vector_type(4))) float f32x4;    // MFMA C/D frag

#define MFMA(a, b, c) __builtin_amdgcn_mfma_f32_16x16x32_bf16((a), (b), (c), 0, 0, 0)

__device__ __forceinline__ short f2bf(float f) {   // RNE float->bf16
    union { float f; unsigned u; } v; v.f = f;
    unsigned r = v.u + 0x7fffu + ((v.u >> 16) & 1u);
    return (short)(r >> 16);
}
__device__ __forceinline__ float bf2f(short s) {
    union { unsigned u; float f; } v; v.u = ((unsigned)(unsigned short)s) << 16; return v.f;
}

// ---------------- prep: bf16 conversion + M-hat precompute (once per launch) ----------------
// M-hat[s][h] is [144][128] bf16: rows r<128: (Kw^T Qw)[r][d] = sum_e Kw[e][r] Qw[e][d]
//   row 128: vvec[d] = sum_e qb[e] Kw[e][d]   (the only softmax-surviving bias term)
//   rows 129..143: zero (padding so the j=8 col-tile's B-frags are defined)
struct PrepArgs {
    const float* csrc[6]; int cend[6];   // conversion segments, cend in float4 units
    const float* K1w; const float* Q1w; const float* Q1b;
    const float* K2w; const float* Q2w; const float* Q2b;
};

__global__ __launch_bounds__(256) void prep_kernel(PrepArgs a, short* __restrict__ dstW,
                                                   short* __restrict__ M1, short* __restrict__ M2) {
    const int blk = blockIdx.x, t = threadIdx.x;
    if (blk < 233) {                     // 233*256 == 59648 float4s exactly
        int i4 = blk * 256 + t;
        int seg = 0;
#pragma unroll
        for (int s = 0; s < 5; s++) seg += (i4 >= a.cend[s]) ? 1 : 0;
        int base = (seg == 0) ? 0 : a.cend[seg - 1];
        float4 v = ((const float4*)a.csrc[seg])[i4 - base];
        short4v o; o.x = f2bf(v.x); o.y = f2bf(v.y); o.z = f2bf(v.z); o.w = f2bf(v.w);
        *(short4v*)(dstW + (size_t)i4 * 4) = o;
    } else {                             // 72 blocks: 8 mats x 9 rowgroups of 16
        int mi = blk - 233;
        int mat = mi / 9, rg = mi % 9;
        int s = mat >> 2, h = mat & 3;
        const float* Kw = s ? a.K2w : a.K1w;
        const float* Qw = s ? a.Q2w : a.Q1w;
        const float* Qb = s ? a.Q2b : a.Q1b;
        short* Mt = (s ? M2 : M1) + h * 144 * 128;
        int r  = rg * 16 + (t >> 4);
        int d0 = (t & 15) * 8;
        float acc[8];
#pragma unroll
        for (int j = 0; j < 8; j++) acc[j] = 0.f;
        const float* kw = Kw + (size_t)h * 16384;
        if (r < 128) {
            const float* qw = Qw + (size_t)h * 16384;
            for (int e = 0; e < 128; e++) {
                float kv = kw[e * 128 + r];
                const float* q = qw + e * 128 + d0;
#pragma unroll
                for (int j = 0; j < 8; j++) acc[j] = fmaf(kv, q[j], acc[j]);
            }
        } else if (r == 128) {
            const float* qb = Qb + h * 128;
            for (int e = 0; e < 128; e++) {
                float qv = qb[e];
                const float* kk = kw + e * 128 + d0;
#pragma unroll
                for (int j = 0; j < 8; j++) acc[j] = fmaf(qv, kk[j], acc[j]);
            }
        }
#pragma unroll
        for (int j = 0; j < 8; j++) Mt[r * 128 + d0 + j] = f2bf(acc[j]);
    }
}

// ---------------- fused attention stage (M-hat path) ----------------
// LDS regions (short offsets), all leading dims == 4 banks mod 32 (free 2-way only):
//   R0 [0,8704):      stage1 X part-1 -> SE [64][136] -> W32 fp32 [64][68]
//   R1 [8704,17408):  stage1 X part-2 / stage2 X -> T [64][136] -> W bf16 [64][72]
//   R2 [17408,19712): VT [32][72]
//   D2 [19712,19840): d2 64 floats
// 39,680 B -> 4 blocks/CU.
#define SE_LD  136
#define T_LD   136
#define VT_LD  72
#define W_LD   72
#define W32_LD 68
#define R1     8704
#define R2     17408
#define D2OFF  19712
#define SMEM_SHORTS 19840

template<int IN, bool XF32>
__global__ __launch_bounds__(256, 4) void attn_stage_kernel(
    const void* __restrict__ xin,                      // [512][64][IN] fp32 (stage1) or bf16 (stage2)
    const short* __restrict__ Ew, const float* __restrict__ Eb,   // Ew bf16 [4][128][IN]
    const short* __restrict__ Mt,                      // [4][144][128] bf16 (M-hat)
    const short* __restrict__ Vw, const float* __restrict__ Vb,   // [4][32][128]
    float* __restrict__ w_out,                          // [4][512][64][64] fp32
    short* __restrict__ x_out)                          // [512][64][128] bf16
{
    __shared__ short sm[SMEM_SHORTS];
    const int tid  = threadIdx.x;
    const int b    = blockIdx.x & 511;   // XCD-affinity: 4 h-blocks of one b share blockIdx%8
    const int h    = blockIdx.x >> 9;
    const int wv   = tid >> 6;
    const int lane = tid & 63;
    const int quad = lane >> 4;
    const int l16  = lane & 15;
    constexpr int NK1   = IN / 32;
    constexpr int XLD   = IN + 8;        // stage1: 264 (spans R0+R1); stage2: 136 (R1)
    constexpr int XBASE = XF32 ? 0 : R1;

    // ---- stage X tile into LDS (bf16) ----
    if constexpr (XF32) {
        const float* xb = (const float*)xin + (size_t)b * 64 * IN;
#pragma unroll
        for (int r = 0; r < 16; r++) {
            int f4 = tid + 256 * r;                     // 4096 float4s
            int row = f4 >> 6, c4 = (f4 & 63) * 4;
            float4 v = ((const float4*)xb)[f4];
            short4v o; o.x = f2bf(v.x); o.y = f2bf(v.y); o.z = f2bf(v.z); o.w = f2bf(v.w);
            *(short4v*)&sm[row * XLD + c4] = o;
        }
    } else {
        const short* xb = (const short*)xin + (size_t)b * 64 * IN;
#pragma unroll
        for (int r = 0; r < 4; r++) {
            int f8 = tid + 256 * r;                     // 1024 short8s
            int row = f8 >> 4, c8 = (f8 & 15) * 8;
            short8 v = *(const short8*)(xb + (size_t)f8 * 8);
            *(short8*)&sm[XBASE + row * 136 + c8] = v;
        }
    }

    // ---- prefetch phase-1 B-frags (E weights) while X staging settles ----
    short8 ebf[NK1 * 2];
    {
        const short* ewh = Ew + (size_t)h * 128 * IN;
#pragma unroll
        for (int k0i = 0; k0i < NK1; k0i++)
#pragma unroll
            for (int j = 0; j < 2; j++)
                ebf[k0i * 2 + j] = *(const short8*)(ewh + (size_t)(wv * 32 + j * 16 + l16) * IN + k0i * 32 + quad * 8);
    }
    __syncthreads();

    short8 mbf[8], xbf[4], vbf[4];   // phase-2 B-frags, prefetched during phase-1 epilogue

    // ---- Phase 1: se = leaky(X @ Ew^T + Eb), col-split: wave -> cols wv*32..+31 ----
    {
        f32x4 acc[4][2];
#pragma unroll
        for (int j = 0; j < 2; j++) {
            float bv = Eb[h * 128 + wv * 32 + j * 16 + l16];
            f32x4 c = {bv, bv, bv, bv};
#pragma unroll
            for (int i = 0; i < 4; i++) acc[i][j] = c;
        }
#pragma unroll
        for (int k0i = 0; k0i < NK1; k0i++) {
            short8 a[4];
#pragma unroll
            for (int i = 0; i < 4; i++)
                a[i] = *(const short8*)&sm[XBASE + (i * 16 + l16) * XLD + k0i * 32 + quad * 8];
#pragma unroll
            for (int i = 0; i < 4; i++)
#pragma unroll
                for (int j = 0; j < 2; j++)
                    acc[i][j] = MFMA(a[i], ebf[k0i * 2 + j], acc[i][j]);
        }
        // prefetch M-hat / extra-tile / Vw frags (fly during epilogue + barriers)
        {
            const short* mth = Mt + (size_t)h * 144 * 128;
#pragma unroll
            for (int k0i = 0; k0i < 4; k0i++) {
#pragma unroll
                for (int j = 0; j < 2; j++)
                    mbf[k0i * 2 + j] = *(const short8*)(mth + (size_t)(wv * 32 + j * 16 + l16) * 128 + k0i * 32 + quad * 8);
                xbf[k0i] = *(const short8*)(mth + (size_t)(128 + l16) * 128 + k0i * 32 + quad * 8);
                vbf[k0i] = *(const short8*)(Vw + (size_t)h * 32 * 128 + (size_t)(((wv >> 1) * 16) + l16) * 128 + k0i * 32 + quad * 8);
            }
        }
        if constexpr (XF32) __syncthreads();   // stage1: SE overlays X part-1
#pragma unroll
        for (int i = 0; i < 4; i++)
#pragma unroll
            for (int j = 0; j < 2; j++)
#pragma unroll
                for (int r = 0; r < 4; r++) {
                    float v = acc[i][j][r];
                    v = (v >= 0.f) ? v : 0.01f * v;
                    sm[(i * 16 + quad * 4 + r) * SE_LD + wv * 32 + j * 16 + l16] = f2bf(v);
                }
    }
    __syncthreads();   // SE published; X dead (T overlays X part-2)

    // ---- Phase 2: T = se @ M-hat (col-split); d2 (wave0); v = leaky(se@Vw^T+Vb) -> VT ----
    {
        f32x4 tacc[4][2], dacc[4];
#pragma unroll
        for (int i = 0; i < 4; i++) {
#pragma unroll
            for (int j = 0; j < 2; j++) tacc[i][j] = (f32x4){0.f, 0.f, 0.f, 0.f};
            dacc[i] = (f32x4){0.f, 0.f, 0.f, 0.f};
        }
#pragma unroll
        for (int k0i = 0; k0i < 4; k0i++) {
            short8 a[4];
#pragma unroll
            for (int i = 0; i < 4; i++)
                a[i] = *(const short8*)&sm[(i * 16 + l16) * SE_LD + k0i * 32 + quad * 8];
#pragma unroll
            for (int i = 0; i < 4; i++)
#pragma unroll
                for (int j = 0; j < 2; j++)
                    tacc[i][j] = MFMA(a[i], mbf[k0i * 2 + j], tacc[i][j]);
            if (wv == 0) {   // wave-uniform branch: extra tile -> d2[m] = vvec . se_m
#pragma unroll
                for (int i = 0; i < 4; i++) dacc[i] = MFMA(a[i], xbf[k0i], dacc[i]);
            }
        }
#pragma unroll
        for (int i = 0; i < 4; i++)
#pragma unroll
            for (int j = 0; j < 2; j++)
#pragma unroll
                for (int r = 0; r < 4; r++)
                    sm[R1 + (i * 16 + quad * 4 + r) * T_LD + wv * 32 + j * 16 + l16] = f2bf(tacc[i][j][r]);
        if (wv == 0 && l16 == 0) {
            float* d2f = (float*)&sm[D2OFF];
#pragma unroll
            for (int i = 0; i < 4; i++)
#pragma unroll
                for (int r = 0; r < 4; r++)
                    d2f[i * 16 + quad * 4 + r] = dacc[i][r];
        }
        // v: wave -> rows (wv&1)*32..+31, cols (wv>>1)*16..+15
        const int n0v = (wv >> 1) * 16, mrow = (wv & 1) * 32;
        float vb = Vb[h * 32 + n0v + l16];
        f32x4 vacc[2]; vacc[0] = (f32x4){vb, vb, vb, vb}; vacc[1] = vacc[0];
#pragma unroll
        for (int k0i = 0; k0i < 4; k0i++) {
            short8 a0 = *(const short8*)&sm[(mrow + l16) * SE_LD + k0i * 32 + quad * 8];
            short8 a1 = *(const short8*)&sm[(mrow + 16 + l16) * SE_LD + k0i * 32 + quad * 8];
            vacc[0] = MFMA(a0, vbf[k0i], vacc[0]);
            vacc[1] = MFMA(a1, vbf[k0i], vacc[1]);
        }
#pragma unroll
        for (int i = 0; i < 2; i++)
#pragma unroll
            for (int r = 0; r < 4; r++) {
                float v = vacc[i][r];
                v = (v >= 0.f) ? v : 0.01f * v;
                sm[R2 + (n0v + l16) * VT_LD + mrow + i * 16 + quad * 4 + r] = f2bf(v);
            }
    }
    __syncthreads();   // T, d2, VT published

    // ---- Phase 3: logits = T @ se^T (row-split: wave -> rows wv*16..+15) ----
    float d2v[4];
    {
        const float* d2f = (const float*)&sm[D2OFF];
#pragma unroll
        for (int jj = 0; jj < 4; jj++) d2v[jj] = d2f[jj * 16 + l16];
    }
    f32x4 lacc[4];
#pragma unroll
    for (int jj = 0; jj < 4; jj++) lacc[jj] = (f32x4){0.f, 0.f, 0.f, 0.f};
#pragma unroll
    for (int k0 = 0; k0 < 128; k0 += 32) {
        short8 a = *(const short8*)&sm[R1 + (wv * 16 + l16) * T_LD + k0 + quad * 8];
#pragma unroll
        for (int jj = 0; jj < 4; jj++) {
            short8 b8 = *(const short8*)&sm[(jj * 16 + l16) * SE_LD + k0 + quad * 8];
            lacc[jj] = MFMA(a, b8, lacc[jj]);
        }
    }
    __syncthreads();   // T, SE dead: W32 overlays SE, W bf16 overlays T

    // ---- softmax (logits + d2[col], row-consts cancel) -> W32 + Wbf16 ----
    {
        const float scale = 0.08838834764831845f;   // 1/sqrt(128)
        float* w32 = (float*)sm;
#pragma unroll
        for (int jj = 0; jj < 4; jj++)
#pragma unroll
            for (int r = 0; r < 4; r++) lacc[jj][r] += d2v[jj];
        float mx[4], inv[4];
#pragma unroll
        for (int r = 0; r < 4; r++) {
            float m = lacc[0][r];
#pragma unroll
            for (int jj = 1; jj < 4; jj++) m = fmaxf(m, lacc[jj][r]);
#pragma unroll
            for (int s = 1; s < 16; s <<= 1) m = fmaxf(m, __shfl_xor(m, s, 16));
            mx[r] = m;
        }
        float sum[4] = {0.f, 0.f, 0.f, 0.f};
#pragma unroll
        for (int jj = 0; jj < 4; jj++)
#pragma unroll
            for (int r = 0; r < 4; r++) {
                float e = __expf((lacc[jj][r] - mx[r]) * scale);
                lacc[jj][r] = e; sum[r] += e;
            }
#pragma unroll
        for (int r = 0; r < 4; r++) {
#pragma unroll
            for (int s = 1; s < 16; s <<= 1) sum[r] += __shfl_xor(sum[r], s, 16);
            inv[r] = 1.0f / sum[r];
        }
#pragma unroll
        for (int r = 0; r < 4; r++) {
            int row = wv * 16 + quad * 4 + r;
#pragma unroll
            for (int jj = 0; jj < 4; jj++) {
                float wval = lacc[jj][r] * inv[r];
                w32[row * W32_LD + jj * 16 + l16] = wval;
                sm[R1 + row * W_LD + jj * 16 + l16] = f2bf(wval);
            }
        }
    }
    __syncthreads();

    // ---- stream w_out (full-line nontemporal float4) ----
    {
        const float* w32 = (const float*)sm;
        float* wbase = w_out + ((size_t)(h * 512 + b)) * 64 * 64;
#pragma unroll
        for (int s = 0; s < 4; s++) {
            int idx = tid + 256 * s;
            int row = idx >> 4, c4 = (idx & 15) * 4;
            f32x4 v = *(const f32x4*)&w32[row * W32_LD + c4];
            __builtin_nontemporal_store(v, (f32x4*)(wbase + idx * 4));
        }
    }

    // ---- Phase 4: att = w @ v -> x_out ----
    {
        f32x4 aacc[2]; aacc[0] = (f32x4){0.f, 0.f, 0.f, 0.f}; aacc[1] = aacc[0];
#pragma unroll
        for (int k0 = 0; k0 < 64; k0 += 32) {
            short8 a = *(const short8*)&sm[R1 + (wv * 16 + l16) * W_LD + k0 + quad * 8];
#pragma unroll
            for (int j = 0; j < 2; j++) {
                short8 b8 = *(const short8*)&sm[R2 + (j * 16 + l16) * VT_LD + k0 + quad * 8];
                aacc[j] = MFMA(a, b8, aacc[j]);
            }
        }
        short* xob = x_out + (size_t)b * 64 * 128;
#pragma unroll
        for (int j = 0; j < 2; j++)
#pragma unroll
            for (int r = 0; r < 4; r++)
                xob[(size_t)(wv * 16 + quad * 4 + r) * 128 + h * 32 + j * 16 + l16] = f2bf(aacc[j][r]);
    }
}

// ---------------- final MLP + softmax, MFMA version ----------------
#define H_LD 72
__global__ __launch_bounds__(256)
void final_mlp_mfma_kernel(const short* __restrict__ x2,    // [32768][128] bf16
                           const short* __restrict__ F1wb,  // [64][128] bf16
                           const float* __restrict__ F1b,   // [64]
                           const short* __restrict__ F2wb,  // [16][64] bf16
                           const float* __restrict__ F2b,   // [16]
                           float* __restrict__ policy)      // [32768][16]
{
    __shared__ short hsm[4][16 * H_LD];
    const int tid  = threadIdx.x;
    const int wv   = tid >> 6;
    const int lane = tid & 63;
    const int quad = lane >> 4;
    const int l16  = lane & 15;
    const int rowbase = blockIdx.x * 64 + wv * 16;

    short8 a[4];
    const short* xrow = x2 + (size_t)(rowbase + l16) * 128;
#pragma unroll
    for (int k = 0; k < 4; k++) a[k] = *(const short8*)(xrow + k * 32 + quad * 8);
    f32x4 acc[4];
#pragma unroll
    for (int j = 0; j < 4; j++) { float bv = F1b[j * 16 + l16]; acc[j] = (f32x4){bv, bv, bv, bv}; }
#pragma unroll
    for (int k = 0; k < 4; k++)
#pragma unroll
        for (int j = 0; j < 4; j++) {
            short8 b8 = *(const short8*)(F1wb + (size_t)(j * 16 + l16) * 128 + k * 32 + quad * 8);
            acc[j] = MFMA(a[k], b8, acc[j]);
        }
    short* hh = &hsm[wv][0];
#pragma unroll
    for (int j = 0; j < 4; j++)
#pragma unroll
        for (int r = 0; r < 4; r++) {
            float v = acc[j][r];
            v = (v >= 0.f) ? v : 0.01f * v;
            hh[(quad * 4 + r) * H_LD + j * 16 + l16] = f2bf(v);
        }
    __syncthreads();

    f32x4 lg;
    { float bv = F2b[l16]; lg = (f32x4){bv, bv, bv, bv}; }
#pragma unroll
    for (int k = 0; k < 2; k++) {
        short8 a2 = *(const short8*)(hh + l16 * H_LD + k * 32 + quad * 8);
        short8 b8 = *(const short8*)(F2wb + (size_t)l16 * 64 + k * 32 + quad * 8);
        lg = MFMA(a2, b8, lg);
    }
#pragma unroll
    for (int r = 0; r < 4; r++) {
        float m = lg[r];
        m = fmaxf(m, __shfl_xor(m, 1, 16));
        m = fmaxf(m, __shfl_xor(m, 2, 16));
        m = fmaxf(m, __shfl_xor(m, 4, 16));
        m = fmaxf(m, __shfl_xor(m, 8, 16));
        float e = __expf(lg[r] - m);
        float s = e;
        s += __shfl_xor(s, 1, 16);
        s += __shfl_xor(s, 2, 16);
        s += __shfl_xor(s, 4, 16);
        s += __shfl_xor(s, 8, 16);
        policy[(size_t)(rowbase + quad * 4 + r) * 16 + l16] = e / s;
    }
}

// ---------------- launcher ----------------
extern "C" void kernel_launch(void* const* d_in, const int* in_sizes, int n_in,
                              void* d_out, int out_size, void* d_ws, size_t ws_size,
                              hipStream_t stream) {
    const float* states = (const float*)d_in[0];
    const float* E1w = (const float*)d_in[1];  const float* E1b = (const float*)d_in[2];
    const float* K1w = (const float*)d_in[3];
    const float* Q1w = (const float*)d_in[5];  const float* Q1b = (const float*)d_in[6];
    const float* V1w = (const float*)d_in[7];  const float* V1b = (const float*)d_in[8];
    const float* E2w = (const float*)d_in[9];  const float* E2b = (const float*)d_in[10];
    const float* K2w = (const float*)d_in[11];
    const float* Q2w = (const float*)d_in[13]; const float* Q2b = (const float*)d_in[14];
    const float* V2w = (const float*)d_in[15]; const float* V2b = (const float*)d_in[16];
    const float* F1w = (const float*)d_in[17]; const float* F1b = (const float*)d_in[18];
    const float* F2w = (const float*)d_in[19]; const float* F2b = (const float*)d_in[20];

    float* out    = (float*)d_out;
    float* policy = out;                        // [512][64][16]
    float* w1     = out + 512 * 64 * 16;        // [4][512][64][64]
    float* w2     = w1 + 4 * 512 * 64 * 64;     // [4][512][64][64]

    // ws layout (shorts): x1b | x2b | bf16 weights | M1 | M2
    short* wsb = (short*)d_ws;
    short* x1b = wsb;
    short* x2b = wsb + 4194304;
    short* wts = wsb + 8388608;
    short* wE1 = wts;            short* wV1 = wts + 131072;
    short* wE2 = wts + 147456;   short* wV2 = wts + 212992;
    short* wF1 = wts + 229376;   short* wF2 = wts + 237568;
    short* M1  = wts + 238592;   short* M2  = M1 + 73728;

    PrepArgs pa;
    pa.csrc[0] = E1w; pa.csrc[1] = V1w; pa.csrc[2] = E2w;
    pa.csrc[3] = V2w; pa.csrc[4] = F1w; pa.csrc[5] = F2w;
    pa.cend[0] = 32768; pa.cend[1] = 36864; pa.cend[2] = 53248;
    pa.cend[3] = 57344; pa.cend[4] = 59392; pa.cend[5] = 59648;
    pa.K1w = K1w; pa.Q1w = Q1w; pa.Q1b = Q1b;
    pa.K2w = K2w; pa.Q2w = Q2w; pa.Q2b = Q2b;
    prep_kernel<<<305, 256, 0, stream>>>(pa, wts, M1, M2);

    attn_stage_kernel<256, true><<<2048, 256, 0, stream>>>(
        (const void*)states, wE1, E1b, M1, wV1, V1b, w1, x1b);
    attn_stage_kernel<128, false><<<2048, 256, 0, stream>>>(
        (const void*)x1b, wE2, E2b, M2, wV2, V2b, w2, x2b);
    final_mlp_mfma_kernel<<<512, 256, 0, stream>>>(x2b, wF1, F1b, wF2, F2b, policy);
}